// Round 2
// baseline (22496.539 us; speedup 1.0000x reference)
//
#include <hip/hip_runtime.h>
#include <hip/hip_bf16.h>

#define NN 50000
#define TT 48
#define FIN 11
#define KH 288          // augmented K for backbone: 256 H + 11 X + 21 pad
#define BROWS 196       // rows per block; 256 blocks covers 50176 >= 50000
// LDS layout (bytes): HT 0..100351 | XT 100352..105055 | RH/HP 105056..162399
#define XT_OFF 100352
#define RH_OFF 105056
#define SMEM_BYTES 162400

typedef __bf16 bf16_t;
typedef __bf16 v8bf __attribute__((ext_vector_type(8)));
typedef float v4f __attribute__((ext_vector_type(4)));

union U16 { uint4 q; v8bf v; uint2 d[2]; };

__device__ __forceinline__ float sigm(float x) { return 1.0f / (1.0f + __expf(-x)); }
__device__ __forceinline__ float tanhfast(float x) {
  float e = __expf(2.0f * x);
  return 1.0f - 2.0f / (e + 1.0f);
}

// Swizzled LDS tile: pitch 256 bf16/row, 16B chunks XORed by (row&31) -> 2-way max conflicts.
__device__ __forceinline__ int sw_chunk(int row, int c) { return row * 256 + ((c ^ (row & 31)) << 3); }
__device__ __forceinline__ int sw_elem(int row, int k) {
  return row * 256 + ((((k >> 3) ^ (row & 31)) << 3) | (k & 7));
}

__device__ __forceinline__ v8bf ldtile(const bf16_t* T, int row, int kt, int quad) {
  U16 u; u.q = *(const uint4*)(T + sw_chunk(row, kt * 4 + quad)); return u.v;
}
// X part of augmented K (kt==8): quad0 -> X cols 0..7, quad1 -> cols 8..11 (col 11 = 0), quads 2,3 -> 0
__device__ __forceinline__ v8bf ldx(const bf16_t* XT, int row, int quad) {
  U16 u;
  u.d[0] = make_uint2(0u, 0u); u.d[1] = make_uint2(0u, 0u);
  if (quad == 0) { u.d[0] = *(const uint2*)(XT + row * 12); u.d[1] = *(const uint2*)(XT + row * 12 + 4); }
  else if (quad == 1) { u.d[0] = *(const uint2*)(XT + row * 12 + 8); }
  return u.v;
}
__device__ __forceinline__ v8bf ldg8(const bf16_t* p) {
  U16 u; u.q = *(const uint4*)p; return u.v;
}

// ---------------- weight/bias packing (bf16, augmented K) ----------------
// Bzr[512][288]: rows 0..255 [Wh0|Wx0|0], rows 256..511 [Wh1|Wx1|0]
// Bh [256][288]: [Wh2|Wx2|0]
// Bu [1024][256]: uWx g0 | uWx g2 | spWx g0 | spWx g2
// Bias[1792]: z | r | h | u0 | u2 | sp0 | sp2  (bx+bh combined)
__global__ void pack_w(const float* __restrict__ bbWx, const float* __restrict__ bbWh,
                       const float* __restrict__ uWx, const float* __restrict__ spWx,
                       const float* __restrict__ bbbx, const float* __restrict__ bbbh,
                       const float* __restrict__ ubx, const float* __restrict__ ubh,
                       const float* __restrict__ spbx, const float* __restrict__ spbh,
                       bf16_t* __restrict__ Bzr, bf16_t* __restrict__ Bh,
                       bf16_t* __restrict__ Bu, float* __restrict__ Bias) {
  int i0 = blockIdx.x * blockDim.x + threadIdx.x;
  int stride = gridDim.x * blockDim.x;
  for (int idx = i0; idx < 512 * KH; idx += stride) {
    int n = idx / KH, k = idx - n * KH;
    int g = n >> 8, nn = n & 255;
    float v = 0.0f;
    if (k < 256) v = bbWh[(g * 256 + nn) * 256 + k];
    else if (k < 256 + FIN) v = bbWx[(g * 256 + nn) * FIN + (k - 256)];
    Bzr[idx] = (bf16_t)v;
  }
  for (int idx = i0; idx < 256 * KH; idx += stride) {
    int n = idx / KH, k = idx - n * KH;
    float v = 0.0f;
    if (k < 256) v = bbWh[(512 + n) * 256 + k];
    else if (k < 256 + FIN) v = bbWx[(512 + n) * FIN + (k - 256)];
    Bh[idx] = (bf16_t)v;
  }
  for (int idx = i0; idx < 1024 * 256; idx += stride) {
    int n = idx >> 8, k = idx & 255;
    int g = n >> 8, nn = n & 255;
    const float* W = (g < 2) ? uWx : spWx;
    int gate = (g & 1) ? 2 : 0;
    Bu[idx] = (bf16_t)W[(gate * 256 + nn) * 256 + k];
  }
  for (int idx = i0; idx < 1792; idx += stride) {
    int seg = idx >> 8, j = idx & 255;
    float v;
    switch (seg) {
      case 0: v = bbbx[j] + bbbh[j]; break;
      case 1: v = bbbx[256 + j] + bbbh[256 + j]; break;
      case 2: v = bbbx[512 + j] + bbbh[512 + j]; break;
      case 3: v = ubx[j] + ubh[j]; break;
      case 4: v = ubx[512 + j] + ubh[512 + j]; break;
      case 5: v = spbx[j] + spbh[j]; break;
      default: v = spbx[512 + j] + spbh[512 + j]; break;
    }
    Bias[idx] = v;
  }
}

// ---------------- persistent fused GRU: one subtile step ----------------
template <int MF>
__device__ __forceinline__ void do_subtile(
    int r0, bf16_t* __restrict__ HT, bf16_t* __restrict__ XT,
    bf16_t* __restrict__ RH, float* __restrict__ HP,
    const bf16_t* __restrict__ Bzr, const bf16_t* __restrict__ Bh,
    const bf16_t* __restrict__ Bu, const float* __restrict__ Bias,
    const float* __restrict__ Wu, const float* __restrict__ Ws, const float* __restrict__ Wp,
    const float* __restrict__ buv, const float* __restrict__ bsv, const float* __restrict__ bpv,
    float* __restrict__ out, int t, int blockRow0, int rlim,
    int lane15, int quad, int wq, int tid) {
  // ===== phase 1: z & r gates (K=288 incl X) =====
  v4f az[MF][4], ar[MF][4];
#pragma unroll
  for (int mf = 0; mf < MF; ++mf)
#pragma unroll
    for (int nf = 0; nf < 4; ++nf) { az[mf][nf] = v4f{0,0,0,0}; ar[mf][nf] = v4f{0,0,0,0}; }
  {
    const bf16_t* bzp[4]; const bf16_t* brp[4];
#pragma unroll
    for (int nf = 0; nf < 4; ++nf) {
      int n = wq * 64 + nf * 16 + lane15;
      bzp[nf] = Bzr + (long)n * KH + quad * 8;
      brp[nf] = Bzr + (long)(256 + n) * KH + quad * 8;
    }
    v8bf bz[4], br[4];
#pragma unroll
    for (int nf = 0; nf < 4; ++nf) { bz[nf] = ldg8(bzp[nf]); br[nf] = ldg8(brp[nf]); }
    for (int kt = 0; kt < 9; ++kt) {
      v8bf nz[4], nr[4];
      if (kt < 8) {
#pragma unroll
        for (int nf = 0; nf < 4; ++nf) { nz[nf] = ldg8(bzp[nf] + (kt + 1) * 32); nr[nf] = ldg8(brp[nf] + (kt + 1) * 32); }
      }
      v8bf a[MF];
#pragma unroll
      for (int mf = 0; mf < MF; ++mf)
        a[mf] = (kt < 8) ? ldtile(HT, r0 + mf * 16 + lane15, kt, quad)
                         : ldx(XT, r0 + mf * 16 + lane15, quad);
#pragma unroll
      for (int mf = 0; mf < MF; ++mf)
#pragma unroll
        for (int nf = 0; nf < 4; ++nf) {
          az[mf][nf] = __builtin_amdgcn_mfma_f32_16x16x32_bf16(a[mf], bz[nf], az[mf][nf], 0, 0, 0);
          ar[mf][nf] = __builtin_amdgcn_mfma_f32_16x16x32_bf16(a[mf], br[nf], ar[mf][nf], 0, 0, 0);
        }
      if (kt < 8) {
#pragma unroll
        for (int nf = 0; nf < 4; ++nf) { bz[nf] = nz[nf]; br[nf] = nr[nf]; }
      }
    }
  }
  // epilogue: z kept in az (registers); rH = sigmoid(r)*Hprev -> RH (subtile-local rows)
#pragma unroll
  for (int nf = 0; nf < 4; ++nf) {
    int col = wq * 64 + nf * 16 + lane15;
    float bzv = Bias[col], brv = Bias[256 + col];
#pragma unroll
    for (int mf = 0; mf < MF; ++mf)
#pragma unroll
      for (int rg = 0; rg < 4; ++rg) {
        int lr = mf * 16 + quad * 4 + rg;
        float zz = sigm(az[mf][nf][rg] + bzv);
        az[mf][nf][rg] = zz;
        float rr = sigm(ar[mf][nf][rg] + brv);
        float hp = (float)HT[sw_elem(r0 + lr, col)];
        RH[sw_elem(lr, col)] = (bf16_t)(rr * hp);
      }
  }
  __syncthreads();

  // ===== phase 2: h_tilde (A = [rH | X]) + H update =====
  {
    v4f ah[MF][4];
#pragma unroll
    for (int mf = 0; mf < MF; ++mf)
#pragma unroll
      for (int nf = 0; nf < 4; ++nf) ah[mf][nf] = v4f{0,0,0,0};
    const bf16_t* bhp[4];
#pragma unroll
    for (int nf = 0; nf < 4; ++nf) {
      int n = wq * 64 + nf * 16 + lane15;
      bhp[nf] = Bh + (long)n * KH + quad * 8;
    }
    v8bf bb[4];
#pragma unroll
    for (int nf = 0; nf < 4; ++nf) bb[nf] = ldg8(bhp[nf]);
    for (int kt = 0; kt < 9; ++kt) {
      v8bf nb[4];
      if (kt < 8) {
#pragma unroll
        for (int nf = 0; nf < 4; ++nf) nb[nf] = ldg8(bhp[nf] + (kt + 1) * 32);
      }
      v8bf a[MF];
#pragma unroll
      for (int mf = 0; mf < MF; ++mf)
        a[mf] = (kt < 8) ? ldtile(RH, mf * 16 + lane15, kt, quad)
                         : ldx(XT, r0 + mf * 16 + lane15, quad);
#pragma unroll
      for (int mf = 0; mf < MF; ++mf)
#pragma unroll
        for (int nf = 0; nf < 4; ++nf)
          ah[mf][nf] = __builtin_amdgcn_mfma_f32_16x16x32_bf16(a[mf], bb[nf], ah[mf][nf], 0, 0, 0);
      if (kt < 8) {
#pragma unroll
        for (int nf = 0; nf < 4; ++nf) bb[nf] = nb[nf];
      }
    }
    // update H in LDS
#pragma unroll
    for (int nf = 0; nf < 4; ++nf) {
      int col = wq * 64 + nf * 16 + lane15;
      float bhv = Bias[512 + col];
#pragma unroll
      for (int mf = 0; mf < MF; ++mf)
#pragma unroll
        for (int rg = 0; rg < 4; ++rg) {
          int lr = mf * 16 + quad * 4 + rg;
          float ht = tanhfast(ah[mf][nf][rg] + bhv);
          float zz = az[mf][nf][rg];
          float hp = (float)HT[sw_elem(r0 + lr, col)];
          float hn = zz * hp + (1.0f - zz) * ht;
          if (r0 + lr < rlim) HT[sw_elem(r0 + lr, col)] = (bf16_t)hn;
        }
    }
  }
  __syncthreads();

  // ===== phase 3: heads (gru_u / gru_sp with H=None => 2 gemms each), fused dots =====
#pragma unroll
  for (int pass = 0; pass < 2; ++pass) {  // 0: u (3 dots), 1: sp (S,P)
    float p0[MF][4], p1[MF][4], p2[MF][4];
#pragma unroll
    for (int mf = 0; mf < MF; ++mf)
#pragma unroll
      for (int rg = 0; rg < 4; ++rg) { p0[mf][rg] = 0.0f; p1[mf][rg] = 0.0f; p2[mf][rg] = 0.0f; }
#pragma unroll
    for (int half = 0; half < 2; ++half) {  // split 64 cols/wave into 2x32 to cap VGPRs
      v4f aZ[MF][2], aH[MF][2];
#pragma unroll
      for (int mf = 0; mf < MF; ++mf)
#pragma unroll
        for (int nfh = 0; nfh < 2; ++nfh) { aZ[mf][nfh] = v4f{0,0,0,0}; aH[mf][nfh] = v4f{0,0,0,0}; }
      const bf16_t* zp[2]; const bf16_t* hp2[2];
#pragma unroll
      for (int nfh = 0; nfh < 2; ++nfh) {
        int n = wq * 64 + (half * 2 + nfh) * 16 + lane15;
        zp[nfh] = Bu + (long)(pass * 512 + n) * 256 + quad * 8;
        hp2[nfh] = Bu + (long)(pass * 512 + 256 + n) * 256 + quad * 8;
      }
      v8bf bz2[2], bh2[2];
#pragma unroll
      for (int nfh = 0; nfh < 2; ++nfh) { bz2[nfh] = ldg8(zp[nfh]); bh2[nfh] = ldg8(hp2[nfh]); }
      for (int kt = 0; kt < 8; ++kt) {
        v8bf nz[2], nh[2];
        if (kt < 7) {
#pragma unroll
          for (int nfh = 0; nfh < 2; ++nfh) { nz[nfh] = ldg8(zp[nfh] + (kt + 1) * 32); nh[nfh] = ldg8(hp2[nfh] + (kt + 1) * 32); }
        }
        v8bf a[MF];
#pragma unroll
        for (int mf = 0; mf < MF; ++mf) a[mf] = ldtile(HT, r0 + mf * 16 + lane15, kt, quad);
#pragma unroll
        for (int mf = 0; mf < MF; ++mf)
#pragma unroll
          for (int nfh = 0; nfh < 2; ++nfh) {
            aZ[mf][nfh] = __builtin_amdgcn_mfma_f32_16x16x32_bf16(a[mf], bz2[nfh], aZ[mf][nfh], 0, 0, 0);
            aH[mf][nfh] = __builtin_amdgcn_mfma_f32_16x16x32_bf16(a[mf], bh2[nfh], aH[mf][nfh], 0, 0, 0);
          }
        if (kt < 7) {
#pragma unroll
          for (int nfh = 0; nfh < 2; ++nfh) { bz2[nfh] = nz[nfh]; bh2[nfh] = nh[nfh]; }
        }
      }
#pragma unroll
      for (int nfh = 0; nfh < 2; ++nfh) {
        int j = wq * 64 + (half * 2 + nfh) * 16 + lane15;
        float g0 = Bias[768 + pass * 512 + j];
        float g2 = Bias[1024 + pass * 512 + j];
        float w0 = pass ? Ws[j] : Wu[j];
        float w1 = pass ? Wp[j] : Wu[256 + j];
        float w2 = pass ? 0.0f : Wu[512 + j];
#pragma unroll
        for (int mf = 0; mf < MF; ++mf)
#pragma unroll
          for (int rg = 0; rg < 4; ++rg) {
            float zz = sigm(aZ[mf][nfh][rg] + g0);
            float ht = tanhfast(aH[mf][nfh][rg] + g2);
            float hc = (1.0f - zz) * ht;  // (1-z)*h_tilde; hu = hc since Hprev=0
            p0[mf][rg] += hc * w0;
            p1[mf][rg] += hc * w1;
            if (pass == 0) p2[mf][rg] += hc * w2;
          }
      }
    }
    // butterfly-reduce over lane15 (the j dimension) and stash per-wave partials
#pragma unroll
    for (int mf = 0; mf < MF; ++mf)
#pragma unroll
      for (int rg = 0; rg < 4; ++rg) {
        float v0 = p0[mf][rg], v1 = p1[mf][rg], v2 = p2[mf][rg];
#pragma unroll
        for (int s = 1; s < 16; s <<= 1) {
          v0 += __shfl_xor(v0, s, 16);
          v1 += __shfl_xor(v1, s, 16);
          if (pass == 0) v2 += __shfl_xor(v2, s, 16);
        }
        int lr = mf * 16 + quad * 4 + rg;
        int nk = pass ? 2 : 3;
        if (lane15 < nk) {
          float vv = (lane15 == 0) ? v0 : ((lane15 == 1) ? v1 : v2);
          HP[lr * 24 + (pass ? 3 + lane15 : lane15) * 4 + wq] = vv;
        }
      }
  }
  __syncthreads();
  // final: sum 4 wave partials, add bias, write U/S/P
  {
    const long SB = (long)TT * NN * 3;
    const long PB = SB + (long)TT * NN;
    for (int o = tid; o < MF * 16 * 5; o += 256) {
      int row = o / 5, k = o - row * 5;
      int lr = r0 + row;
      if (lr < rlim) {
        long m = (long)blockRow0 + lr;
        float s = HP[row * 24 + k * 4 + 0] + HP[row * 24 + k * 4 + 1] +
                  HP[row * 24 + k * 4 + 2] + HP[row * 24 + k * 4 + 3];
        if (k < 3)       out[(long)t * (NN * 3) + m * 3 + k] = s + buv[k];
        else if (k == 3) out[SB + (long)t * NN + m] = s + bsv[0];
        else             out[PB + (long)t * NN + m] = s + bpv[0];
      }
    }
  }
  __syncthreads();
}

__global__ void __launch_bounds__(256, 1) fused_gru(
    const float* __restrict__ X,
    const bf16_t* __restrict__ Bzr, const bf16_t* __restrict__ Bh,
    const bf16_t* __restrict__ Bu, const float* __restrict__ Bias,
    const float* __restrict__ Wu, const float* __restrict__ buv,
    const float* __restrict__ Ws, const float* __restrict__ bsv,
    const float* __restrict__ Wp, const float* __restrict__ bpv,
    float* __restrict__ out) {
  extern __shared__ char smem[];
  bf16_t* HT = (bf16_t*)smem;
  bf16_t* XT = (bf16_t*)(smem + XT_OFF);
  bf16_t* RH = (bf16_t*)(smem + RH_OFF);
  float* HP = (float*)(smem + RH_OFF);
  const int tid = threadIdx.x;
  const int lane15 = tid & 15, quad = (tid & 63) >> 4, wq = tid >> 6;
  const int blockRow0 = blockIdx.x * BROWS;
  const int rlim = min(BROWS, NN - blockRow0);

  // zero H tile + X tile (incl pad col 11)
  for (int i = tid; i < RH_OFF / 16; i += 256) ((uint4*)smem)[i] = make_uint4(0, 0, 0, 0);
  __syncthreads();
  // stage X_0
  for (int i = tid; i < BROWS * FIN; i += 256) {
    int r = i / FIN, f = i - r * FIN;
    float v = (blockRow0 + r < NN) ? X[((long)blockRow0 + r) * FIN + f] : 0.0f;
    XT[r * 12 + f] = (bf16_t)v;
  }
  __syncthreads();

  for (int t = 0; t < TT; ++t) {
    do_subtile<7>(0, HT, XT, RH, HP, Bzr, Bh, Bu, Bias, Wu, Ws, Wp, buv, bsv, bpv,
                  out, t, blockRow0, rlim, lane15, quad, wq, tid);
    do_subtile<6>(112, HT, XT, RH, HP, Bzr, Bh, Bu, Bias, Wu, Ws, Wp, buv, bsv, bpv,
                  out, t, blockRow0, rlim, lane15, quad, wq, tid);
    // stage X_{t+1}
    if (t + 1 < TT) {
      for (int i = tid; i < BROWS * FIN; i += 256) {
        int r = i / FIN, f = i - r * FIN;
        float v = (blockRow0 + r < NN) ? X[((long)(t + 1) * NN + blockRow0 + r) * FIN + f] : 0.0f;
        XT[r * 12 + f] = (bf16_t)v;
      }
    }
    __syncthreads();
  }
}

extern "C" void kernel_launch(void* const* d_in, const int* in_sizes, int n_in,
                              void* d_out, int out_size, void* d_ws, size_t ws_size,
                              hipStream_t stream) {
  const float* X    = (const float*)d_in[0];
  // d_in[1] edge_index unused (ChebConv K=1 ignores edges)
  const float* bbWx = (const float*)d_in[2];
  const float* bbbx = (const float*)d_in[3];
  const float* bbWh = (const float*)d_in[4];
  const float* bbbh = (const float*)d_in[5];
  const float* uWx  = (const float*)d_in[6];
  const float* ubx  = (const float*)d_in[7];
  const float* ubh  = (const float*)d_in[9];   // u_Wh (d_in[8]) dead: H=None
  const float* spWx = (const float*)d_in[10];
  const float* spbx = (const float*)d_in[11];
  const float* spbh = (const float*)d_in[13];  // sp_Wh (d_in[12]) dead
  const float* Wu   = (const float*)d_in[14];
  const float* buv  = (const float*)d_in[15];
  const float* Ws   = (const float*)d_in[16];
  const float* bsv  = (const float*)d_in[17];
  const float* Wp   = (const float*)d_in[18];
  const float* bpv  = (const float*)d_in[19];
  float* out = (float*)d_out;

  char* ws = (char*)d_ws;
  bf16_t* Bzr  = (bf16_t*)(ws);            // 512*288*2  = 294,912
  bf16_t* Bh   = (bf16_t*)(ws + 294912);   // 256*288*2  = 147,456
  bf16_t* Bu   = (bf16_t*)(ws + 442368);   // 1024*256*2 = 524,288
  float*  Bias = (float*)(ws + 966656);    // 1792*4     = 7,168
  if (ws_size < (size_t)(1 << 20)) return;

  // enable >64KB dynamic LDS (idempotent; host-side, not stream-ordered)
  hipFuncSetAttribute((const void*)fused_gru, hipFuncAttributeMaxDynamicSharedMemorySize,
                      SMEM_BYTES);

  pack_w<<<dim3(192), dim3(256), 0, stream>>>(bbWx, bbWh, uWx, spWx,
                                              bbbx, bbbh, ubx, ubh, spbx, spbh,
                                              Bzr, Bh, Bu, Bias);
  fused_gru<<<dim3(256), dim3(256), SMEM_BYTES, stream>>>(
      X, Bzr, Bh, Bu, Bias, Wu, buv, Ws, bsv, Wp, bpv, out);
}